// Round 1
// baseline (476.801 us; speedup 1.0000x reference)
//
#include <hip/hip_runtime.h>
#include <hip/hip_bf16.h>

typedef __attribute__((ext_vector_type(8))) short bf16x8;
typedef __attribute__((ext_vector_type(4))) float f32x4;

#define TH 0.01f

constexpr int D   = 512;    // input/output feature dim
constexpr int F   = 2048;   // hidden dim
constexpr int BM  = 64;     // rows per block
constexpr int FC  = 128;    // F-chunk
constexpr int BK  = 64;     // K staging step for GEMM1
constexpr int XS_LD = D + 8;    // 520
constexpr int W1_LD = BK + 8;   // 72
constexpr int HS_LD = FC + 8;   // 136

static __device__ __forceinline__ short f2bf(float f) {
  union { float f; unsigned u; } v; v.f = f;
  unsigned r = v.u + 0x7FFFu + ((v.u >> 16) & 1u);  // RNE
  return (short)(r >> 16);
}

// Convert + transpose weights to bf16 so B-operand fragments are k-contiguous.
// w1 [D][F] fp32 -> w1t [F][D] bf16 ; w2 [F][D] fp32 -> w2t [D][F] bf16
__global__ void prep_weights(const float* __restrict__ w1, const float* __restrict__ w2,
                             short* __restrict__ w1t, short* __restrict__ w2t) {
  int idx = blockIdx.x * 256 + threadIdx.x;
  if (idx >= D * F) return;
  {
    int d = idx / F, f = idx % F;
    w1t[f * D + d] = f2bf(w1[idx]);
  }
  {
    int f = idx / D, d = idx % D;
    w2t[d * F + f] = f2bf(w2[idx]);
  }
}

__global__ __launch_bounds__(512)
void ffn_fused(const float* __restrict__ x,
               const float* __restrict__ b1,
               const float* __restrict__ b2,
               const short* __restrict__ w1t,
               const short* __restrict__ w2t,
               float* __restrict__ out) {
  __shared__ short xs[BM][XS_LD];     // 66,560 B  x tile (bf16), resident all chunks
  __shared__ short w1s[FC][W1_LD];    // 18,432 B  w1t chunk [FC cols][BK k]
  __shared__ short hs[BM][HS_LD];     // 17,408 B  h tile (bf16)
  __shared__ unsigned spike[BM];

  const int tid  = threadIdx.x;
  const int row0 = blockIdx.x * BM;

  if (tid < BM) spike[tid] = 0u;
  __syncthreads();

  // ---- load x tile -> bf16 LDS, compute spike mask (8 threads per row) ----
  {
    int r = tid >> 3, seg = tid & 7;
    const float4* xr = (const float4*)(x + (size_t)(row0 + r) * D + seg * 64);
    short* xrow = &xs[r][seg * 64];
    bool any = false;
#pragma unroll
    for (int i = 0; i < 16; ++i) {
      float4 v = xr[i];
      any = any || fabsf(v.x) > TH || fabsf(v.y) > TH ||
                   fabsf(v.z) > TH || fabsf(v.w) > TH;
      short4 s;
      s.x = f2bf(v.x); s.y = f2bf(v.y); s.z = f2bf(v.z); s.w = f2bf(v.w);
      *(short4*)(xrow + i * 4) = s;
    }
    if (any) atomicOr(&spike[r], 1u);
  }
  __syncthreads();

  const int lane = tid & 63;
  const int wid  = tid >> 6;   // 8 waves: 2 (row) x 4 (col)
  const int wr   = wid >> 2;   // 0..1
  const int wc   = wid & 3;    // 0..3
  const int l15  = lane & 15;
  const int lk   = lane >> 4;  // 0..3

  f32x4 oacc[2][8];            // rows wr*32+fm*16, cols wc*128+fn*16
#pragma unroll
  for (int i = 0; i < 2; ++i)
#pragma unroll
    for (int j = 0; j < 8; ++j) oacc[i][j] = f32x4{0.f, 0.f, 0.f, 0.f};

  for (int fc = 0; fc < F; fc += FC) {
    // ================= GEMM1: h[64][128] = x[64][512] @ w1[:, fc:fc+128] ===
    f32x4 hacc[2][2];
#pragma unroll
    for (int i = 0; i < 2; ++i)
#pragma unroll
      for (int j = 0; j < 2; ++j) hacc[i][j] = f32x4{0.f, 0.f, 0.f, 0.f};

    for (int k0 = 0; k0 < D; k0 += BK) {
      // stage w1t[fc+c][k0:k0+64] -> w1s[c][:], 1024 x 16B, 2 per thread
#pragma unroll
      for (int t = 0; t < 2; ++t) {
        int j = tid + t * 512;
        int c = j >> 3, k8 = (j & 7) * 8;
        *(bf16x8*)&w1s[c][k8] =
            *(const bf16x8*)&w1t[(size_t)(fc + c) * D + k0 + k8];
      }
      __syncthreads();
#pragma unroll
      for (int ks = 0; ks < 2; ++ks) {
        bf16x8 a0 = *(const bf16x8*)&xs[wr * 32 + l15     ][k0 + ks * 32 + lk * 8];
        bf16x8 a1 = *(const bf16x8*)&xs[wr * 32 + 16 + l15][k0 + ks * 32 + lk * 8];
        bf16x8 g0 = *(const bf16x8*)&w1s[wc * 32 + l15     ][ks * 32 + lk * 8];
        bf16x8 g1 = *(const bf16x8*)&w1s[wc * 32 + 16 + l15][ks * 32 + lk * 8];
        hacc[0][0] = __builtin_amdgcn_mfma_f32_16x16x32_bf16(a0, g0, hacc[0][0], 0, 0, 0);
        hacc[0][1] = __builtin_amdgcn_mfma_f32_16x16x32_bf16(a0, g1, hacc[0][1], 0, 0, 0);
        hacc[1][0] = __builtin_amdgcn_mfma_f32_16x16x32_bf16(a1, g0, hacc[1][0], 0, 0, 0);
        hacc[1][1] = __builtin_amdgcn_mfma_f32_16x16x32_bf16(a1, g1, hacc[1][1], 0, 0, 0);
      }
      __syncthreads();  // w1s reads done before next stage / hs write phase
    }

    // ---- bias + relu + write h tile (C/D layout: col=l15, row=lk*4+r) ----
#pragma unroll
    for (int fm = 0; fm < 2; ++fm)
#pragma unroll
      for (int fn = 0; fn < 2; ++fn) {
        int col = wc * 32 + fn * 16 + l15;
        float bias = b1[fc + col];
        int rbase = wr * 32 + fm * 16 + lk * 4;
#pragma unroll
        for (int r = 0; r < 4; ++r) {
          float v = hacc[fm][fn][r] + bias;
          hs[rbase + r][col] = f2bf(fmaxf(v, 0.f));
        }
      }
    __syncthreads();  // hs visible

    // ===== GEMM2 partial: oacc += h[64][fc:fc+128] @ w2[fc:fc+128][:] =====
#pragma unroll
    for (int ks = 0; ks < 4; ++ks) {
      bf16x8 a0 = *(const bf16x8*)&hs[wr * 32 + l15     ][ks * 32 + lk * 8];
      bf16x8 a1 = *(const bf16x8*)&hs[wr * 32 + 16 + l15][ks * 32 + lk * 8];
#pragma unroll
      for (int fn = 0; fn < 8; ++fn) {
        int col = wc * 128 + fn * 16 + l15;
        bf16x8 g = *(const bf16x8*)&w2t[(size_t)col * F + fc + ks * 32 + lk * 8];
        oacc[0][fn] = __builtin_amdgcn_mfma_f32_16x16x32_bf16(a0, g, oacc[0][fn], 0, 0, 0);
        oacc[1][fn] = __builtin_amdgcn_mfma_f32_16x16x32_bf16(a1, g, oacc[1][fn], 0, 0, 0);
      }
    }
    __syncthreads();  // hs reads done before next chunk overwrites
  }

  // ---- epilogue: + b2, spike mask, store ----
#pragma unroll
  for (int fn = 0; fn < 8; ++fn) {
    int col = wc * 128 + fn * 16 + l15;
    float bias = b2[col];
#pragma unroll
    for (int fm = 0; fm < 2; ++fm) {
      int rbase = wr * 32 + fm * 16 + lk * 4;
#pragma unroll
      for (int r = 0; r < 4; ++r) {
        int row = rbase + r;
        float v = oacc[fm][fn][r] + bias;
        out[(size_t)(row0 + row) * D + col] = spike[row] ? v : 0.f;
      }
    }
  }
}

extern "C" void kernel_launch(void* const* d_in, const int* in_sizes, int n_in,
                              void* d_out, int out_size, void* d_ws, size_t ws_size,
                              hipStream_t stream) {
  const float* x  = (const float*)d_in[0];
  const float* w1 = (const float*)d_in[1];
  const float* b1 = (const float*)d_in[2];
  const float* w2 = (const float*)d_in[3];
  const float* b2 = (const float*)d_in[4];
  float* out = (float*)d_out;

  short* w1t = (short*)d_ws;                  // [F][D] bf16, 2 MB
  short* w2t = w1t + (size_t)D * F;           // [D][F] bf16, 2 MB

  prep_weights<<<(D * F + 255) / 256, 256, 0, stream>>>(w1, w2, w1t, w2t);

  int M = out_size / D;                       // 32768 rows
  ffn_fused<<<M / BM, 512, 0, stream>>>(x, b1, b2, w1t, w2t, out);
}

// Round 2
// 186.077 us; speedup vs baseline: 2.5624x; 2.5624x over previous
//
#include <hip/hip_runtime.h>
#include <hip/hip_bf16.h>

typedef __attribute__((ext_vector_type(8))) short bf16x8;
typedef __attribute__((ext_vector_type(4))) float f32x4;

#define TH 0.01f
#define MFMA(a, b, c) __builtin_amdgcn_mfma_f32_16x16x32_bf16(a, b, c, 0, 0, 0)

constexpr int D  = 512;   // in/out feature dim
constexpr int F  = 2048;  // hidden dim
constexpr int NC = 32;    // F chunks of 64

static __device__ __forceinline__ short f2bf(float f) {
  union { float f; unsigned u; } v; v.f = f;
  unsigned r = v.u + 0x7FFFu + ((v.u >> 16) & 1u);  // RNE
  return (short)(r >> 16);
}

static __device__ __forceinline__ void gl16(const void* g, char* l) {
  __builtin_amdgcn_global_load_lds(
      (const __attribute__((address_space(1))) unsigned*)g,
      (__attribute__((address_space(3))) unsigned*)l, 16, 0, 0);
}

// ---------------------------------------------------------------------------
// Staged weight layouts (consumed linearly by global_load_lds, swizzle baked
// into the source permutation so the swizzled ds_read sees the right data):
//
// w1_staged: 64 regions of 32KB. region = chunk*2 + half  (half: k 0..255 / 256..511)
//   short q in region: col = q>>8 (hcol 0..63), k_in_half = (q&255) ^ ((col&7)<<3)
//   element = bf16( w1[(half*256 + k_in_half) * F + chunk*64 + col] )
//
// w2_staged: 64 regions of 32KB. region = chunk*2 + sub   (sub: k 0..31 / 32..63)
//   short q: col = q>>5 (0..511), k_in_sub = (q&31) ^ (((col>>1)&3)<<3)
//   element = bf16( w2[(chunk*64 + sub*32 + k_in_sub) * D + col] )
// ---------------------------------------------------------------------------
__global__ void prep_weights(const float* __restrict__ w1, const float* __restrict__ w2,
                             short* __restrict__ w1s, short* __restrict__ w2s) {
  int g = blockIdx.x * 256 + threadIdx.x;
  if (g < 131072) {  // w1 granule (16B)
    int region = g >> 11, chunk = region >> 1, half = region & 1;
    int q0  = (g & 2047) << 3;
    int col = q0 >> 8;
    int kb  = ((q0 & 255) ^ ((col & 7) << 3)) + (half << 8);
    int fcol = (chunk << 6) + col;
    bf16x8 v;
#pragma unroll
    for (int j = 0; j < 8; ++j) v[j] = f2bf(w1[(size_t)(kb + j) * F + fcol]);
    *(bf16x8*)(w1s + (size_t)g * 8) = v;
  } else {
    int h = g - 131072;
    int region = h >> 11, chunk = region >> 1, sub = region & 1;
    int q0  = (h & 2047) << 3;
    int col = q0 >> 5;
    int kb  = ((q0 & 31) ^ (((col >> 1) & 3) << 3)) + (chunk << 6) + (sub << 5);
    bf16x8 v;
#pragma unroll
    for (int j = 0; j < 8; ++j) v[j] = f2bf(w2[(size_t)(kb + j) * D + col]);
    *(bf16x8*)(w2s + (size_t)h * 8) = v;
  }
}

// LDS map (dynamic, 150784 B):
//   0      : w1 slot0 (k 0..255)   32768
//   32768  : w1 slot1 (k 256..511) 32768
//   65536  : w2 sub0  (k 0..31)    32768
//   98304  : w2 sub1  (k 32..63)   32768
//   131072 : hs [64 rows][72 cols] bf16  9216
//   140288 : b1s f32[2048]         8192
//   148480 : b2s f32[512]          2048
//   150528 : spike u32[64]          256
__global__ __launch_bounds__(512, 2)
void ffn_fused(const float* __restrict__ x,
               const float* __restrict__ b1,
               const float* __restrict__ b2,
               const char* __restrict__ w1g,
               const char* __restrict__ w2g,
               float* __restrict__ out) {
  extern __shared__ char smem[];
  short*    w1s0 = (short*)(smem);
  short*    w1s1 = (short*)(smem + 32768);
  short*    w2p0 = (short*)(smem + 65536);
  short*    w2p1 = (short*)(smem + 98304);
  short*    hs   = (short*)(smem + 131072);
  float*    b1s  = (float*)(smem + 140288);
  float*    b2s  = (float*)(smem + 148480);
  unsigned* spk  = (unsigned*)(smem + 150528);

  const int tid  = threadIdx.x;
  const int lane = tid & 63, wid = tid >> 6;
  const int l15  = lane & 15, lk = lane >> 4;
  const int row0 = blockIdx.x * 64;

  // ---------------- prologue ----------------
  // issue w1 chunk 0 (both halves, regions 0..1 -> slots 0..1), 8 loads/thread-
  // group: stays in flight under the x-load/convert below.
#pragma unroll
  for (int t = 0; t < 8; ++t)
    gl16(w1g + (size_t)(t * 512 + tid) * 16, smem + (t * 512 + tid) * 16);

  // biases -> LDS (keeps ALL ordinary VMEM out of the main loop)
  *(float4*)&b1s[tid * 4] = *(const float4*)&b1[tid * 4];
  if (tid < 128) *(float4*)&b2s[tid * 4] = *(const float4*)&b2[tid * 4];

  // x tile -> registers (B-operand fragments of swapped GEMM1) + spike mask.
  // Wave handles rows (wid&3)*16 .. +15 (waves wid and wid+4 duplicate).
  const int xrow = (wid & 3) * 16 + l15;
  const float* xp = x + (size_t)(row0 + xrow) * D + lk * 8;
  bf16x8 xr[16];
  bool any = false;
#pragma unroll
  for (int ks = 0; ks < 16; ++ks) {
    float4 f0 = *(const float4*)(xp + ks * 32);
    float4 f1 = *(const float4*)(xp + ks * 32 + 4);
    any = any | (fabsf(f0.x) > TH) | (fabsf(f0.y) > TH) | (fabsf(f0.z) > TH) |
          (fabsf(f0.w) > TH) | (fabsf(f1.x) > TH) | (fabsf(f1.y) > TH) |
          (fabsf(f1.z) > TH) | (fabsf(f1.w) > TH);
    bf16x8 v;
    v[0] = f2bf(f0.x); v[1] = f2bf(f0.y); v[2] = f2bf(f0.z); v[3] = f2bf(f0.w);
    v[4] = f2bf(f1.x); v[5] = f2bf(f1.y); v[6] = f2bf(f1.z); v[7] = f2bf(f1.w);
    xr[ks] = v;
  }
  unsigned a = any ? 1u : 0u;
  a |= __shfl_xor(a, 16, 64);
  a |= __shfl_xor(a, 32, 64);
  if (wid < 4 && lane < 16) spk[xrow] = a;

  asm volatile("s_waitcnt vmcnt(4) lgkmcnt(0)" ::: "memory");  // slot0 landed
  __builtin_amdgcn_s_barrier();

  // wave roles
  const int c00 = (wid >> 2) * 32;       // GEMM1: hcol frags c00, c00+16
  const int c01 = c00 + 16;
  const int R0  = (wid >> 2) * 32;       // GEMM2: out rows R0..R0+31
  const int C0  = (wid & 3) * 128;       // GEMM2: out cols C0..C0+127

  f32x4 oacc[2][8];
#pragma unroll
  for (int m = 0; m < 2; ++m)
#pragma unroll
    for (int n = 0; n < 8; ++n) oacc[m][n] = f32x4{0.f, 0.f, 0.f, 0.f};

  // ---------------- main loop: 32 chunks of FC=64 ----------------
  // Steady-state queue (per-thread 16B loads, oldest first) and waits:
  //  P1: +w2[i](8)        | A: vmcnt(8)  (w1[i]h1 done)
  //  P2: +w1[i+1]h0(4)    | B: vmcnt(4)  (w2[i] done)     [tail: vmcnt(0)]
  //  P3: +w1[i+1]h1(4)    | C: vmcnt(4)  (w1[i+1]h0 done) [tail: skip]
  for (int i = 0; i < NC; ++i) {
    f32x4 h0 = {0.f, 0.f, 0.f, 0.f}, h1 = {0.f, 0.f, 0.f, 0.f};

    // ---- P1: GEMM1 k 0..255 (slot0); issue w2[i] both subs ----
    {
      const char* src = w2g + (size_t)i * 65536;
#pragma unroll
      for (int t = 0; t < 8; ++t)
        gl16(src + (size_t)(t * 512 + tid) * 16, smem + 65536 + (t * 512 + tid) * 16);
    }
    __builtin_amdgcn_s_setprio(1);
#pragma unroll
    for (int s = 0; s < 8; ++s) {
      int o0 = ((c00 + l15) << 8) + (s << 5) + (lk << 3); o0 ^= ((c00 + l15) & 7) << 3;
      int o1 = ((c01 + l15) << 8) + (s << 5) + (lk << 3); o1 ^= ((c01 + l15) & 7) << 3;
      h0 = MFMA(*(const bf16x8*)(w1s0 + o0), xr[s], h0);
      h1 = MFMA(*(const bf16x8*)(w1s0 + o1), xr[s], h1);
    }
    __builtin_amdgcn_s_setprio(0);
    asm volatile("s_waitcnt vmcnt(8) lgkmcnt(0)" ::: "memory");
    __builtin_amdgcn_s_barrier();

    // ---- P2: GEMM1 k 256..511 (slot1); issue w1[i+1]h0 -> slot0 ----
    if (i + 1 < NC) {
      const char* src = w1g + (size_t)(i + 1) * 65536;
#pragma unroll
      for (int t = 0; t < 4; ++t)
        gl16(src + (size_t)(t * 512 + tid) * 16, smem + (t * 512 + tid) * 16);
    }
    __builtin_amdgcn_s_setprio(1);
#pragma unroll
    for (int s = 0; s < 8; ++s) {
      int o0 = ((c00 + l15) << 8) + (s << 5) + (lk << 3); o0 ^= ((c00 + l15) & 7) << 3;
      int o1 = ((c01 + l15) << 8) + (s << 5) + (lk << 3); o1 ^= ((c01 + l15) & 7) << 3;
      h0 = MFMA(*(const bf16x8*)(w1s1 + o0), xr[s + 8], h0);
      h1 = MFMA(*(const bf16x8*)(w1s1 + o1), xr[s + 8], h1);
    }
    __builtin_amdgcn_s_setprio(0);
    // bias + relu + pack -> hs[row][hcol] (lane holds 4 consecutive hcols of
    // one h-row: contiguous ds_write_b64)
    {
      float4 bv0 = *(const float4*)&b1s[i * 64 + c00 + lk * 4];
      float4 bv1 = *(const float4*)&b1s[i * 64 + c01 + lk * 4];
      short4 p0, p1;
      p0.x = f2bf(fmaxf(h0[0] + bv0.x, 0.f)); p0.y = f2bf(fmaxf(h0[1] + bv0.y, 0.f));
      p0.z = f2bf(fmaxf(h0[2] + bv0.z, 0.f)); p0.w = f2bf(fmaxf(h0[3] + bv0.w, 0.f));
      p1.x = f2bf(fmaxf(h1[0] + bv1.x, 0.f)); p1.y = f2bf(fmaxf(h1[1] + bv1.y, 0.f));
      p1.z = f2bf(fmaxf(h1[2] + bv1.z, 0.f)); p1.w = f2bf(fmaxf(h1[3] + bv1.w, 0.f));
      *(short4*)&hs[xrow * 72 + c00 + lk * 4] = p0;
      *(short4*)&hs[xrow * 72 + c01 + lk * 4] = p1;
    }
    if (i + 1 < NC) asm volatile("s_waitcnt vmcnt(4) lgkmcnt(0)" ::: "memory");
    else            asm volatile("s_waitcnt vmcnt(0) lgkmcnt(0)" ::: "memory");
    __builtin_amdgcn_s_barrier();

    // ---- P3: GEMM2 (K=64 of this chunk); issue w1[i+1]h1 -> slot1 ----
    if (i + 1 < NC) {
      const char* src = w1g + (size_t)(i + 1) * 65536 + 32768;
#pragma unroll
      for (int t = 0; t < 4; ++t)
        gl16(src + (size_t)(t * 512 + tid) * 16, smem + 32768 + (t * 512 + tid) * 16);
    }
    __builtin_amdgcn_s_setprio(1);
#pragma unroll
    for (int ks = 0; ks < 2; ++ks) {
      const short* w2p = ks ? w2p1 : w2p0;
      bf16x8 a0 = *(const bf16x8*)&hs[(R0 + l15) * 72 + ks * 32 + lk * 8];
      bf16x8 a1 = *(const bf16x8*)&hs[(R0 + 16 + l15) * 72 + ks * 32 + lk * 8];
#pragma unroll
      for (int fn = 0; fn < 8; ++fn) {
        int col = C0 + fn * 16 + l15;
        int o = (col << 5) + (lk << 3); o ^= ((col >> 1) & 3) << 3;
        bf16x8 g = *(const bf16x8*)(w2p + o);
        oacc[0][fn] = MFMA(a0, g, oacc[0][fn]);
        oacc[1][fn] = MFMA(a1, g, oacc[1][fn]);
      }
    }
    __builtin_amdgcn_s_setprio(0);
    if (i + 1 < NC) {
      asm volatile("s_waitcnt vmcnt(4) lgkmcnt(0)" ::: "memory");
      __builtin_amdgcn_s_barrier();
    }
  }

  // ---------------- epilogue: + b2, spike mask, store ----------------
  unsigned s0[4], s1[4];
#pragma unroll
  for (int r = 0; r < 4; ++r) {
    s0[r] = spk[R0 + lk * 4 + r];
    s1[r] = spk[R0 + 16 + lk * 4 + r];
  }
#pragma unroll
  for (int fn = 0; fn < 8; ++fn) {
    int col = C0 + fn * 16 + l15;
    float bias = b2s[col];
#pragma unroll
    for (int r = 0; r < 4; ++r) {
      int row = R0 + lk * 4 + r;
      float v = oacc[0][fn][r] + bias;
      out[(size_t)(row0 + row) * D + col] = s0[r] ? v : 0.f;
    }
#pragma unroll
    for (int r = 0; r < 4; ++r) {
      int row = R0 + 16 + lk * 4 + r;
      float v = oacc[1][fn][r] + bias;
      out[(size_t)(row0 + row) * D + col] = s1[r] ? v : 0.f;
    }
  }
}

extern "C" void kernel_launch(void* const* d_in, const int* in_sizes, int n_in,
                              void* d_out, int out_size, void* d_ws, size_t ws_size,
                              hipStream_t stream) {
  const float* x  = (const float*)d_in[0];
  const float* w1 = (const float*)d_in[1];
  const float* b1 = (const float*)d_in[2];
  const float* w2 = (const float*)d_in[3];
  const float* b2 = (const float*)d_in[4];
  float* out = (float*)d_out;

  short* w1staged = (short*)d_ws;                    // 2 MB
  short* w2staged = w1staged + (size_t)D * F;        // 2 MB

  prep_weights<<<1024, 256, 0, stream>>>(w1, w2, w1staged, w2staged);

  static_assert(sizeof(float4) == 16, "");
  (void)hipFuncSetAttribute((const void*)ffn_fused,
                            hipFuncAttributeMaxDynamicSharedMemorySize, 150784);
  int M = out_size / D;  // 32768
  ffn_fused<<<M / 64, 512, 150784, stream>>>(x, b1, b2, (const char*)w1staged,
                                             (const char*)w2staged, out);
}